// Round 3
// baseline (1070.604 us; speedup 1.0000x reference)
//
#include <hip/hip_runtime.h>
#include <hip/hip_bf16.h>

#define NN 100000
#define NE 625000
#define HH 128
#define DOUT 64
#define NHTOT (NN * HH)          // 12,800,000 feature elements
#define SCAN_B 391               // ceil(NN/256)
#define WTOT 107712              // canonical weight element count

// canonical weight offsets (elements)
#define OW_Wl  0
#define OW_bl  49152
#define OW_Wr  49536
#define OW_gam 98688
#define OW_bet 99072
#define OW_Wo  99456
#define OW_bo  107648

typedef unsigned int u32;
typedef unsigned short u16;
typedef long long i64;

__device__ __forceinline__ float bflo(u32 v) { return __uint_as_float(v << 16); }
__device__ __forceinline__ float bfhi(u32 v) { return __uint_as_float(v & 0xffff0000u); }
__device__ __forceinline__ float bf2f(u16 u) { return __uint_as_float(((u32)u) << 16); }
__device__ __forceinline__ u16 f2b(float f) {
    __hip_bfloat16 h = __float2bfloat16(f);   // RNE
    return *(u16*)&h;
}
__device__ __forceinline__ int edge_at(const void* ei, int is64, i64 idx) {
    return is64 ? (int)((const i64*)ei)[idx] : ((const int*)ei)[idx];
}

// ---- dtype sniffer: flags[0]=1 if x is fp32, flags[1]=1 if edge_index is int64 ----
__global__ void k_sniff(const u16* __restrict__ x, const int* __restrict__ ei,
                        int* __restrict__ flags) {
    __shared__ int cbad, cnz;
    int t = threadIdx.x;
    if (t == 0) { cbad = 0; cnz = 0; }
    __syncthreads();
    u16 u = x[t];                       // first 256 u16 of x buffer
    int e = (u >> 7) & 0xff;            // bf16 exponent field
    if (e >= 132) atomicAdd(&cbad, 1);  // |v|>=32 or NaN/inf: impossible for bf16 N(0,1)
    if (t < 32) { if (ei[2 * t + 1] != 0) atomicAdd(&cnz, 1); }
    __syncthreads();
    if (t == 0) {
        flags[0] = (cbad > 4) ? 1 : 0;  // fp32 floats
        flags[1] = (cnz == 0) ? 1 : 0;  // int64 edges
    }
}

// ---- canonicalize x -> bf16 buffer ----
__global__ void k_cvt(const void* __restrict__ xin, uint2* __restrict__ out,
                      const int* __restrict__ flags) {
    int gid = blockIdx.x * 256 + threadIdx.x;   // grid = NHTOT/4/256 exact
    if (flags[0]) {
        float4 v = ((const float4*)xin)[gid];
        uint2 r;
        r.x = (u32)f2b(v.x) | ((u32)f2b(v.y) << 16);
        r.y = (u32)f2b(v.z) | ((u32)f2b(v.w) << 16);
        out[gid] = r;
    } else {
        out[gid] = ((const uint2*)xin)[gid];
    }
}

// ---- canonicalize all weights/biases -> bf16 ----
__global__ void k_cvtw(const void* Wl, const void* bl, const void* Wr,
                       const void* gam, const void* bet, const void* Wo,
                       const void* bo, u16* __restrict__ wc,
                       const int* __restrict__ flags) {
    int gid = blockIdx.x * 256 + threadIdx.x;
    if (gid >= WTOT) return;
    const void* p; int li;
    if      (gid < OW_bl)  { p = Wl;  li = gid; }
    else if (gid < OW_Wr)  { p = bl;  li = gid - OW_bl; }
    else if (gid < OW_gam) { p = Wr;  li = gid - OW_Wr; }
    else if (gid < OW_bet) { p = gam; li = gid - OW_gam; }
    else if (gid < OW_Wo)  { p = bet; li = gid - OW_bet; }
    else if (gid < OW_bo)  { p = Wo;  li = gid - OW_Wo; }
    else                   { p = bo;  li = gid - OW_bo; }
    wc[gid] = flags[0] ? f2b(((const float*)p)[li]) : ((const u16*)p)[li];
}

// ---- degree histogram over dst ----
__global__ void k_hist(const void* __restrict__ ei, int* __restrict__ cnt,
                       const int* __restrict__ flags) {
    int e = blockIdx.x * 256 + threadIdx.x;
    if (e < NE) {
        int d = edge_at(ei, flags[1], (i64)NE + e);
        if ((unsigned)d < NN) atomicAdd(&cnt[d], 1);
    }
}

// ---- scan step 1: per-block sums ----
__global__ void k_scan1(const int* __restrict__ cnt, int* __restrict__ part) {
    __shared__ int sh[256];
    int t = threadIdx.x, g = blockIdx.x * 256 + t;
    sh[t] = (g < NN) ? cnt[g] : 0;
    __syncthreads();
    for (int s = 128; s > 0; s >>= 1) { if (t < s) sh[t] += sh[t + s]; __syncthreads(); }
    if (t == 0) part[blockIdx.x] = sh[0];
}

// ---- scan step 2: exclusive scan of SCAN_B partials ----
__global__ void k_scan2(int* part) {
    __shared__ int sh[512];
    int t = threadIdx.x;
    int v = (t < SCAN_B) ? part[t] : 0;
    sh[t] = v; __syncthreads();
    for (int off = 1; off < 512; off <<= 1) {
        int a = (t >= off) ? sh[t - off] : 0;
        __syncthreads(); sh[t] += a; __syncthreads();
    }
    if (t < SCAN_B) part[t] = sh[t] - v;   // exclusive
}

// ---- scan step 3: offsets, cursor, invdeg ----
__global__ void k_scan3(const int* __restrict__ cnt, const int* __restrict__ part,
                        int* __restrict__ offs, int* __restrict__ cur,
                        float* __restrict__ invdeg) {
    __shared__ int sh[256];
    int t = threadIdx.x, g = blockIdx.x * 256 + t;
    int c = (g < NN) ? cnt[g] : 0;
    sh[t] = c; __syncthreads();
    for (int off = 1; off < 256; off <<= 1) {
        int a = (t >= off) ? sh[t - off] : 0;
        __syncthreads(); sh[t] += a; __syncthreads();
    }
    if (g < NN) {
        int start = part[blockIdx.x] + sh[t] - c;
        offs[g] = start; cur[g] = start;
        invdeg[g] = 1.0f / fmaxf((float)c, 1.0f);
        if (g == NN - 1) offs[NN] = start + c;
    }
}

// ---- counting-sort src by dst ----
__global__ void k_sort(const void* __restrict__ ei, int* __restrict__ cur,
                       int* __restrict__ ssrc, const int* __restrict__ flags) {
    int e = blockIdx.x * 256 + threadIdx.x;
    if (e < NE) {
        int is64 = flags[1];
        int d = edge_at(ei, is64, (i64)NE + e);
        int s = edge_at(ei, is64, (i64)e);
        if ((unsigned)d < NN) {
            int p = atomicAdd(&cur[d], 1);
            if ((unsigned)p < NE) ssrc[p] = s;
        }
    }
}

// ---- aggregation: one wave per destination node, no atomics, bf16 rows ----
__global__ void k_agg(const u32* __restrict__ X, const int* __restrict__ offs,
                      const int* __restrict__ ssrc, const float* __restrict__ invdeg,
                      u32* __restrict__ AGG) {
    int wid = (blockIdx.x * 256 + threadIdx.x) >> 6;
    int lane = threadIdx.x & 63;
    if (wid >= NN) return;
    int s0 = offs[wid], s1 = offs[wid + 1];
    float a0 = 0.f, a1 = 0.f;
    for (int j = s0; j < s1; ++j) {
        int s = ssrc[j];
        s = min(max(s, 0), NN - 1);          // defensive clamp
        u32 v = X[(size_t)s * 64 + lane];    // 2 bf16 feats per lane
        a0 += bflo(v); a1 += bfhi(v);
    }
    float iv = invdeg[wid];
    u32 r = (u32)f2b(a0 * iv) | ((u32)f2b(a1 * iv) << 16);
    AGG[(size_t)wid * 64 + lane] = r;
}

// ---- fused dual-GEMM + bias + residual + LayerNorm + ReLU (bf16 in/out, fp32 acc) ----
__global__ __launch_bounds__(256) void k_gemm(
        const u16* __restrict__ X, u16* __restrict__ AGG,
        const u16* __restrict__ Wl, const u16* __restrict__ Wr,
        const u16* __restrict__ bl, const u16* __restrict__ gam,
        const u16* __restrict__ bet, int residual) {
    __shared__ u32  WsS[128 * 64];   // 32 KB: W row f, u32-col c swizzled by f&30
    __shared__ float AtS[128 * 64];  // 32 KB: A^T row k, col n swizzled by k>>2
    int tid = threadIdx.x;
    int tx = tid & 15, ty = tid >> 4;
    int n0 = blockIdx.x * 64;

    float acc[8][4];
    #pragma unroll
    for (int i = 0; i < 8; ++i)
        #pragma unroll
        for (int j = 0; j < 4; ++j) acc[i][j] = 0.f;

    for (int p = 0; p < 2; ++p) {
        if (p) __syncthreads();
        const u32* Wm = (const u32*)(p ? Wr : Wl);
        #pragma unroll
        for (int it = 0; it < 16; ++it) {
            int idx = it * 256 + tid;
            int f = idx >> 5, cp = (idx & 31) * 2;
            uint2 wv = *((const uint2*)(Wm + f * 64 + cp));
            int tt = f & 30;
            *((uint2*)&WsS[f * 64 + (cp ^ tt)]) = wv;
        }
        const u16* Asrc = p ? X : AGG;
        #pragma unroll
        for (int it = 0; it < 8; ++it) {
            int idx = it * 256 + tid;
            int nl = idx >> 5, c4 = idx & 31;
            int ng = n0 + nl;
            uint2 raw = make_uint2(0u, 0u);
            if (ng < NN) raw = ((const uint2*)Asrc)[(size_t)ng * 32 + c4];
            int col = nl ^ c4, rb = 4 * c4;
            AtS[(rb + 0) * 64 + col] = bflo(raw.x);
            AtS[(rb + 1) * 64 + col] = bfhi(raw.x);
            AtS[(rb + 2) * 64 + col] = bflo(raw.y);
            AtS[(rb + 3) * 64 + col] = bfhi(raw.y);
        }
        __syncthreads();
        for (int k = 0; k < 128; k += 4) {
            int s = (k >> 2) & 31;
            float a[4][4];
            #pragma unroll
            for (int kk = 0; kk < 4; ++kk) {
                const float* row = &AtS[(k + kk) * 64];
                #pragma unroll
                for (int j = 0; j < 4; ++j) a[kk][j] = row[(4 * ty + j) ^ s];
            }
            int c0 = k >> 1;
            #pragma unroll
            for (int i = 0; i < 8; ++i) {
                int f = tx + 16 * i, tt = f & 30;
                uint2 wv = *((const uint2*)&WsS[f * 64 + (c0 ^ tt)]);
                float w0 = bflo(wv.x), w1 = bfhi(wv.x), w2 = bflo(wv.y), w3 = bfhi(wv.y);
                #pragma unroll
                for (int j = 0; j < 4; ++j)
                    acc[i][j] += w0 * a[0][j] + w1 * a[1][j] + w2 * a[2][j] + w3 * a[3][j];
            }
        }
    }
    // epilogue: bias + residual + LN + relu  (AtS still holds X tile fp32)
    float s1[4] = {0, 0, 0, 0}, s2[4] = {0, 0, 0, 0};
    #pragma unroll
    for (int i = 0; i < 8; ++i) {
        int f = tx + 16 * i;
        float bv = bf2f(bl[f]);
        int sres = (f >> 2) & 31;
        #pragma unroll
        for (int j = 0; j < 4; ++j) {
            float r = residual ? AtS[f * 64 + ((4 * ty + j) ^ sres)] : 0.f;
            float v = acc[i][j] + bv + r;
            acc[i][j] = v;
            s1[j] += v; s2[j] += v * v;
        }
    }
    #pragma unroll
    for (int m = 1; m < 16; m <<= 1) {
        #pragma unroll
        for (int j = 0; j < 4; ++j) {
            s1[j] += __shfl_xor(s1[j], m, 64);
            s2[j] += __shfl_xor(s2[j], m, 64);
        }
    }
    float mu[4], rs[4];
    #pragma unroll
    for (int j = 0; j < 4; ++j) {
        mu[j] = s1[j] * (1.0f / 128.0f);
        float var = s2[j] * (1.0f / 128.0f) - mu[j] * mu[j];
        rs[j] = rsqrtf(fmaxf(var, 0.f) + 1e-5f);
    }
    #pragma unroll
    for (int i = 0; i < 8; ++i) {
        int f = tx + 16 * i;
        float g = bf2f(gam[f]), b = bf2f(bet[f]);
        #pragma unroll
        for (int j = 0; j < 4; ++j) {
            int ng = n0 + 4 * ty + j;
            if (ng < NN) {
                float v = (acc[i][j] - mu[j]) * rs[j] * g + b;
                AGG[(size_t)ng * 128 + f] = f2b(fmaxf(v, 0.f));
            }
        }
    }
}

// ---- final projection: out = x3 @ Wo^T + bo ----
__global__ void k_proj(const u16* __restrict__ X, const u16* __restrict__ Wo,
                       const u16* __restrict__ bo, void* __restrict__ out,
                       const int* __restrict__ flags) {
    int gid = blockIdx.x * 256 + threadIdx.x;
    int n = gid >> 6, f = gid & 63;
    if (n >= NN) return;
    const uint2* xr = (const uint2*)(X + (size_t)n * 128);
    const uint2* wr = (const uint2*)((const u32*)Wo + f * 64);
    float acc = 0.f;
    #pragma unroll 8
    for (int c = 0; c < 32; ++c) {
        uint2 wv = wr[c];
        uint2 xv = xr[c];
        acc += bflo(wv.x) * bflo(xv.x) + bfhi(wv.x) * bfhi(xv.x)
             + bflo(wv.y) * bflo(xv.y) + bfhi(wv.y) * bfhi(xv.y);
    }
    acc += bf2f(bo[f]);
    if (flags[0]) ((float*)out)[gid] = acc;
    else          ((u16*)out)[gid]   = f2b(acc);
}

extern "C" void kernel_launch(void* const* d_in, const int* in_sizes, int n_in,
                              void* d_out, int out_size, void* d_ws, size_t ws_size,
                              hipStream_t stream) {
    const void* xin = d_in[0];
    const void* ei  = d_in[1];     // [2][NE]: row0=src, row1=dst (int32 or int64)

    // workspace layout: 2 bf16 feature buffers + canonical weights + CSR aux (~56 MB)
    u16*   xc     = (u16*)d_ws;                 // NHTOT bf16
    u16*   b0     = xc + NHTOT;                 // NHTOT bf16
    u16*   wc     = b0 + NHTOT;                 // WTOT (padded to 107776)
    float* invdeg = (float*)(wc + 107776);      // NN
    int*   cnt    = (int*)(invdeg + NN);        // NN
    int*   cur    = cnt + NN;                   // NN
    int*   offs   = cur + NN;                   // NN+1
    int*   ssrc   = offs + NN + 1;              // NE
    int*   part   = ssrc + NE;                  // 512
    int*   flags  = part + 512;                 // 2

    k_sniff<<<1, 256, 0, stream>>>((const u16*)xin, (const int*)ei, flags);
    hipMemsetAsync(cnt, 0, NN * sizeof(int), stream);
    hipMemsetAsync(ssrc, 0, NE * sizeof(int), stream);   // insurance vs poison
    k_cvt <<<NHTOT / 4 / 256, 256, 0, stream>>>(xin, (uint2*)xc, flags);
    k_cvtw<<<(WTOT + 255) / 256, 256, 0, stream>>>(d_in[2], d_in[3], d_in[4],
            d_in[5], d_in[6], d_in[7], d_in[8], wc, flags);
    k_hist<<<(NE + 255) / 256, 256, 0, stream>>>(ei, cnt, flags);
    k_scan1<<<SCAN_B, 256, 0, stream>>>(cnt, part);
    k_scan2<<<1, 512, 0, stream>>>(part);
    k_scan3<<<SCAN_B, 256, 0, stream>>>(cnt, part, offs, cur, invdeg);
    k_sort<<<(NE + 255) / 256, 256, 0, stream>>>(ei, cur, ssrc, flags);

    const u16* Wl  = wc + OW_Wl;
    const u16* bl  = wc + OW_bl;
    const u16* Wr  = wc + OW_Wr;
    const u16* gam = wc + OW_gam;
    const u16* bet = wc + OW_bet;
    const u16* Wo  = wc + OW_Wo;
    const u16* bo  = wc + OW_bo;

    // layer 0: X=xc, agg->b0, gemm in place over b0
    k_agg<<<(NN * 64) / 256, 256, 0, stream>>>((const u32*)xc, offs, ssrc, invdeg, (u32*)b0);
    k_gemm<<<(NN + 63) / 64, 256, 0, stream>>>(xc, b0, Wl, Wr, bl, gam, bet, 0);
    // layer 1: X=b0, agg->xc (input x dead), gemm in place over xc
    k_agg<<<(NN * 64) / 256, 256, 0, stream>>>((const u32*)b0, offs, ssrc, invdeg, (u32*)xc);
    k_gemm<<<(NN + 63) / 64, 256, 0, stream>>>(b0, xc,
            Wl + HH * HH, Wr + HH * HH, bl + HH, gam + HH, bet + HH, 1);
    // layer 2: X=xc, agg->b0 (x1 dead), gemm in place over b0
    k_agg<<<(NN * 64) / 256, 256, 0, stream>>>((const u32*)xc, offs, ssrc, invdeg, (u32*)b0);
    k_gemm<<<(NN + 63) / 64, 256, 0, stream>>>(xc, b0,
            Wl + 2 * HH * HH, Wr + 2 * HH * HH, bl + 2 * HH, gam + 2 * HH, bet + 2 * HH, 1);

    k_proj<<<(NN * DOUT) / 256, 256, 0, stream>>>(b0, Wo, bo, d_out, flags);
}

// Round 4
// 636.900 us; speedup vs baseline: 1.6810x; 1.6810x over previous
//
#include <hip/hip_runtime.h>
#include <hip/hip_bf16.h>

#define NN 100000
#define NE 625000
#define HH 128
#define DOUT 64
#define NHTOT (NN * HH)          // 12,800,000 feature elements
#define SCAN_B 391               // ceil(NN/256)
#define WTOT 107712              // canonical weight element count

// canonical weight offsets (elements)
#define OW_Wl  0
#define OW_bl  49152
#define OW_Wr  49536
#define OW_gam 98688
#define OW_bet 99072
#define OW_Wo  99456
#define OW_bo  107648

typedef unsigned int u32;
typedef unsigned short u16;
typedef long long i64;
typedef short bf16x8 __attribute__((ext_vector_type(8)));   // 8 bf16 = 4 VGPR
typedef float f32x4 __attribute__((ext_vector_type(4)));

__device__ __forceinline__ float bflo(u32 v) { return __uint_as_float(v << 16); }
__device__ __forceinline__ float bfhi(u32 v) { return __uint_as_float(v & 0xffff0000u); }
__device__ __forceinline__ float bf2f(u16 u) { return __uint_as_float(((u32)u) << 16); }
__device__ __forceinline__ u16 f2b(float f) {
    __hip_bfloat16 h = __float2bfloat16(f);   // RNE
    return *(u16*)&h;
}
__device__ __forceinline__ int edge_at(const void* ei, int is64, i64 idx) {
    return is64 ? (int)((const i64*)ei)[idx] : ((const int*)ei)[idx];
}

// ---- dtype sniffer: flags[0]=1 if x is fp32, flags[1]=1 if edge_index is int64 ----
__global__ void k_sniff(const u16* __restrict__ x, const int* __restrict__ ei,
                        int* __restrict__ flags) {
    __shared__ int cbad, cnz;
    int t = threadIdx.x;
    if (t == 0) { cbad = 0; cnz = 0; }
    __syncthreads();
    u16 u = x[t];
    int e = (u >> 7) & 0xff;            // bf16 exponent field
    if (e >= 132) atomicAdd(&cbad, 1);
    if (t < 32) { if (ei[2 * t + 1] != 0) atomicAdd(&cnz, 1); }
    __syncthreads();
    if (t == 0) {
        flags[0] = (cbad > 4) ? 1 : 0;  // fp32 floats
        flags[1] = (cnz == 0) ? 1 : 0;  // int64 edges
    }
}

// ---- canonicalize x -> bf16 buffer ----
__global__ void k_cvt(const void* __restrict__ xin, uint2* __restrict__ out,
                      const int* __restrict__ flags) {
    int gid = blockIdx.x * 256 + threadIdx.x;   // grid = NHTOT/4/256 exact
    if (flags[0]) {
        float4 v = ((const float4*)xin)[gid];
        uint2 r;
        r.x = (u32)f2b(v.x) | ((u32)f2b(v.y) << 16);
        r.y = (u32)f2b(v.z) | ((u32)f2b(v.w) << 16);
        out[gid] = r;
    } else {
        out[gid] = ((const uint2*)xin)[gid];
    }
}

// ---- canonicalize all weights/biases -> bf16 ----
__global__ void k_cvtw(const void* Wl, const void* bl, const void* Wr,
                       const void* gam, const void* bet, const void* Wo,
                       const void* bo, u16* __restrict__ wc,
                       const int* __restrict__ flags) {
    int gid = blockIdx.x * 256 + threadIdx.x;
    if (gid >= WTOT) return;
    const void* p; int li;
    if      (gid < OW_bl)  { p = Wl;  li = gid; }
    else if (gid < OW_Wr)  { p = bl;  li = gid - OW_bl; }
    else if (gid < OW_gam) { p = Wr;  li = gid - OW_Wr; }
    else if (gid < OW_bet) { p = gam; li = gid - OW_gam; }
    else if (gid < OW_Wo)  { p = bet; li = gid - OW_bet; }
    else if (gid < OW_bo)  { p = Wo;  li = gid - OW_Wo; }
    else                   { p = bo;  li = gid - OW_bo; }
    wc[gid] = flags[0] ? f2b(((const float*)p)[li]) : ((const u16*)p)[li];
}

// ---- degree histogram over dst ----
__global__ void k_hist(const void* __restrict__ ei, int* __restrict__ cnt,
                       const int* __restrict__ flags) {
    int e = blockIdx.x * 256 + threadIdx.x;
    if (e < NE) {
        int d = edge_at(ei, flags[1], (i64)NE + e);
        if ((unsigned)d < NN) atomicAdd(&cnt[d], 1);
    }
}

// ---- scan step 1: per-block sums ----
__global__ void k_scan1(const int* __restrict__ cnt, int* __restrict__ part) {
    __shared__ int sh[256];
    int t = threadIdx.x, g = blockIdx.x * 256 + t;
    sh[t] = (g < NN) ? cnt[g] : 0;
    __syncthreads();
    for (int s = 128; s > 0; s >>= 1) { if (t < s) sh[t] += sh[t + s]; __syncthreads(); }
    if (t == 0) part[blockIdx.x] = sh[0];
}

// ---- scan step 2: exclusive scan of SCAN_B partials ----
__global__ void k_scan2(int* part) {
    __shared__ int sh[512];
    int t = threadIdx.x;
    int v = (t < SCAN_B) ? part[t] : 0;
    sh[t] = v; __syncthreads();
    for (int off = 1; off < 512; off <<= 1) {
        int a = (t >= off) ? sh[t - off] : 0;
        __syncthreads(); sh[t] += a; __syncthreads();
    }
    if (t < SCAN_B) part[t] = sh[t] - v;   // exclusive
}

// ---- scan step 3: offsets, cursor, invdeg ----
__global__ void k_scan3(const int* __restrict__ cnt, const int* __restrict__ part,
                        int* __restrict__ offs, int* __restrict__ cur,
                        float* __restrict__ invdeg) {
    __shared__ int sh[256];
    int t = threadIdx.x, g = blockIdx.x * 256 + t;
    int c = (g < NN) ? cnt[g] : 0;
    sh[t] = c; __syncthreads();
    for (int off = 1; off < 256; off <<= 1) {
        int a = (t >= off) ? sh[t - off] : 0;
        __syncthreads(); sh[t] += a; __syncthreads();
    }
    if (g < NN) {
        int start = part[blockIdx.x] + sh[t] - c;
        offs[g] = start; cur[g] = start;
        invdeg[g] = 1.0f / fmaxf((float)c, 1.0f);
        if (g == NN - 1) offs[NN] = start + c;
    }
}

// ---- counting-sort src by dst ----
__global__ void k_sort(const void* __restrict__ ei, int* __restrict__ cur,
                       int* __restrict__ ssrc, const int* __restrict__ flags) {
    int e = blockIdx.x * 256 + threadIdx.x;
    if (e < NE) {
        int is64 = flags[1];
        int d = edge_at(ei, is64, (i64)NE + e);
        int s = edge_at(ei, is64, (i64)e);
        if ((unsigned)d < NN) {
            int p = atomicAdd(&cur[d], 1);
            if ((unsigned)p < NE) ssrc[p] = s;
        }
    }
}

// ---- aggregation: one wave per destination node, no atomics, bf16 rows ----
__global__ void k_agg(const u32* __restrict__ X, const int* __restrict__ offs,
                      const int* __restrict__ ssrc, const float* __restrict__ invdeg,
                      u32* __restrict__ AGG) {
    int wid = (blockIdx.x * 256 + threadIdx.x) >> 6;
    int lane = threadIdx.x & 63;
    if (wid >= NN) return;
    int s0 = offs[wid], s1 = offs[wid + 1];
    float a0 = 0.f, a1 = 0.f;
    for (int j = s0; j < s1; ++j) {
        int s = ssrc[j];
        s = min(max(s, 0), NN - 1);
        u32 v = X[(size_t)s * 64 + lane];
        a0 += bflo(v); a1 += bfhi(v);
    }
    float iv = invdeg[wid];
    u32 r = (u32)f2b(a0 * iv) | ((u32)f2b(a1 * iv) << 16);
    AGG[(size_t)wid * 64 + lane] = r;
}

// ---- MFMA fused dual-GEMM + bias + residual + LayerNorm + ReLU ----
// One wave = 16 nodes, all 128 output feats. A-frags & B-frags load directly
// from global (contiguous 16B/lane); no LDS, no barriers.
// A-layout: lane m=lane&15 -> node, k=quad*8+j. B-layout: lane n=lane&15 -> feat row.
// C/D: row(node)=quad*4+reg, col(feat)=lane&15. K=256 = [AGG(128)|X(128)].
__global__ __launch_bounds__(256) void k_gemm(
        const u16* __restrict__ X, u16* __restrict__ AGG,
        const u16* __restrict__ Wl, const u16* __restrict__ Wr,
        const u16* __restrict__ bl, const u16* __restrict__ gam,
        const u16* __restrict__ bet, int residual) {
    int tid = threadIdx.x;
    int wave = tid >> 6, lane = tid & 63;
    int mn = lane & 15, quad = lane >> 4;
    int n0 = (blockIdx.x * 4 + wave) * 16;
    if (n0 >= NN) return;

    int ngc = min(n0 + mn, NN - 1);
    const u16* arow = AGG + (size_t)ngc * HH;
    const u16* xrow = X   + (size_t)ngc * HH;
    bf16x8 afr[8];
    #pragma unroll
    for (int kt = 0; kt < 4; ++kt)
        afr[kt] = *(const bf16x8*)(arow + kt * 32 + quad * 8);
    #pragma unroll
    for (int kt = 0; kt < 4; ++kt)
        afr[4 + kt] = *(const bf16x8*)(xrow + kt * 32 + quad * 8);

    f32x4 acc[8];
    #pragma unroll
    for (int ft = 0; ft < 8; ++ft) acc[ft] = (f32x4){0.f, 0.f, 0.f, 0.f};

    #pragma unroll
    for (int ft = 0; ft < 8; ++ft) {
        const u16* wlrow = Wl + (size_t)(ft * 16 + mn) * HH;
        const u16* wrrow = Wr + (size_t)(ft * 16 + mn) * HH;
        #pragma unroll
        for (int kt = 0; kt < 4; ++kt) {
            bf16x8 b = *(const bf16x8*)(wlrow + kt * 32 + quad * 8);
            acc[ft] = __builtin_amdgcn_mfma_f32_16x16x32_bf16(afr[kt], b, acc[ft], 0, 0, 0);
        }
        #pragma unroll
        for (int kt = 0; kt < 4; ++kt) {
            bf16x8 b = *(const bf16x8*)(wrrow + kt * 32 + quad * 8);
            acc[ft] = __builtin_amdgcn_mfma_f32_16x16x32_bf16(afr[4 + kt], b, acc[ft], 0, 0, 0);
        }
    }

    // epilogue: bias + residual + LN + relu
    float s1[4] = {0, 0, 0, 0}, s2[4] = {0, 0, 0, 0};
    #pragma unroll
    for (int ft = 0; ft < 8; ++ft) {
        int f = ft * 16 + mn;
        float bv = bf2f(bl[f]);
        #pragma unroll
        for (int r = 0; r < 4; ++r) {
            int nd = n0 + quad * 4 + r;
            int ndc = min(nd, NN - 1);
            float res = residual ? bf2f(X[(size_t)ndc * HH + f]) : 0.f;
            float v = acc[ft][r] + bv + res;
            acc[ft][r] = v;
            s1[r] += v; s2[r] += v * v;
        }
    }
    #pragma unroll
    for (int msk = 1; msk < 16; msk <<= 1) {
        #pragma unroll
        for (int r = 0; r < 4; ++r) {
            s1[r] += __shfl_xor(s1[r], msk, 64);
            s2[r] += __shfl_xor(s2[r], msk, 64);
        }
    }
    float mu[4], rs[4];
    #pragma unroll
    for (int r = 0; r < 4; ++r) {
        mu[r] = s1[r] * (1.0f / 128.0f);
        float var = s2[r] * (1.0f / 128.0f) - mu[r] * mu[r];
        rs[r] = rsqrtf(fmaxf(var, 0.f) + 1e-5f);
    }
    #pragma unroll
    for (int ft = 0; ft < 8; ++ft) {
        int f = ft * 16 + mn;
        float g = bf2f(gam[f]), b = bf2f(bet[f]);
        #pragma unroll
        for (int r = 0; r < 4; ++r) {
            int nd = n0 + quad * 4 + r;
            if (nd < NN) {
                float v = (acc[ft][r] - mu[r]) * rs[r] * g + b;
                AGG[(size_t)nd * HH + f] = f2b(fmaxf(v, 0.f));
            }
        }
    }
}

// ---- MFMA final projection: out = x3 @ Wo^T + bo ----
__global__ __launch_bounds__(256) void k_proj(
        const u16* __restrict__ Xf, const u16* __restrict__ Wo,
        const u16* __restrict__ bo, void* __restrict__ out,
        const int* __restrict__ flags) {
    int tid = threadIdx.x;
    int wave = tid >> 6, lane = tid & 63;
    int mn = lane & 15, quad = lane >> 4;
    int n0 = (blockIdx.x * 4 + wave) * 16;
    if (n0 >= NN) return;

    int ngc = min(n0 + mn, NN - 1);
    const u16* xrow = Xf + (size_t)ngc * HH;
    bf16x8 afr[4];
    #pragma unroll
    for (int kt = 0; kt < 4; ++kt)
        afr[kt] = *(const bf16x8*)(xrow + kt * 32 + quad * 8);

    f32x4 acc[4];
    #pragma unroll
    for (int ft = 0; ft < 4; ++ft) acc[ft] = (f32x4){0.f, 0.f, 0.f, 0.f};
    #pragma unroll
    for (int ft = 0; ft < 4; ++ft) {
        const u16* worow = Wo + (size_t)(ft * 16 + mn) * HH;
        #pragma unroll
        for (int kt = 0; kt < 4; ++kt) {
            bf16x8 b = *(const bf16x8*)(worow + kt * 32 + quad * 8);
            acc[ft] = __builtin_amdgcn_mfma_f32_16x16x32_bf16(afr[kt], b, acc[ft], 0, 0, 0);
        }
    }
    int isf32 = flags[0];
    #pragma unroll
    for (int ft = 0; ft < 4; ++ft) {
        int f = ft * 16 + mn;
        float bv = bf2f(bo[f]);
        #pragma unroll
        for (int r = 0; r < 4; ++r) {
            int nd = n0 + quad * 4 + r;
            if (nd < NN) {
                float v = acc[ft][r] + bv;
                if (isf32) ((float*)out)[(size_t)nd * DOUT + f] = v;
                else       ((u16*)out)[(size_t)nd * DOUT + f]   = f2b(v);
            }
        }
    }
}

extern "C" void kernel_launch(void* const* d_in, const int* in_sizes, int n_in,
                              void* d_out, int out_size, void* d_ws, size_t ws_size,
                              hipStream_t stream) {
    const void* xin = d_in[0];
    const void* ei  = d_in[1];     // [2][NE]: row0=src, row1=dst

    u16*   xc     = (u16*)d_ws;                 // NHTOT bf16
    u16*   b0     = xc + NHTOT;                 // NHTOT bf16
    u16*   wc     = b0 + NHTOT;                 // WTOT (padded to 107776)
    float* invdeg = (float*)(wc + 107776);      // NN
    int*   cnt    = (int*)(invdeg + NN);        // NN
    int*   cur    = cnt + NN;                   // NN
    int*   offs   = cur + NN;                   // NN+1
    int*   ssrc   = offs + NN + 1;              // NE
    int*   part   = ssrc + NE;                  // 512
    int*   flags  = part + 512;                 // 2

    k_sniff<<<1, 256, 0, stream>>>((const u16*)xin, (const int*)ei, flags);
    hipMemsetAsync(cnt, 0, NN * sizeof(int), stream);
    hipMemsetAsync(ssrc, 0, NE * sizeof(int), stream);
    k_cvt <<<NHTOT / 4 / 256, 256, 0, stream>>>(xin, (uint2*)xc, flags);
    k_cvtw<<<(WTOT + 255) / 256, 256, 0, stream>>>(d_in[2], d_in[3], d_in[4],
            d_in[5], d_in[6], d_in[7], d_in[8], wc, flags);
    k_hist<<<(NE + 255) / 256, 256, 0, stream>>>(ei, cnt, flags);
    k_scan1<<<SCAN_B, 256, 0, stream>>>(cnt, part);
    k_scan2<<<1, 512, 0, stream>>>(part);
    k_scan3<<<SCAN_B, 256, 0, stream>>>(cnt, part, offs, cur, invdeg);
    k_sort<<<(NE + 255) / 256, 256, 0, stream>>>(ei, cur, ssrc, flags);

    const u16* Wl  = wc + OW_Wl;
    const u16* bl  = wc + OW_bl;
    const u16* Wr  = wc + OW_Wr;
    const u16* gam = wc + OW_gam;
    const u16* bet = wc + OW_bet;
    const u16* Wo  = wc + OW_Wo;
    const u16* bo  = wc + OW_bo;

    int gblk = (NN + 63) / 64;   // 64 nodes per block (4 waves x 16)
    // layer 0: X=xc, agg->b0, gemm in place over b0
    k_agg<<<(NN * 64) / 256, 256, 0, stream>>>((const u32*)xc, offs, ssrc, invdeg, (u32*)b0);
    k_gemm<<<gblk, 256, 0, stream>>>(xc, b0, Wl, Wr, bl, gam, bet, 0);
    // layer 1: X=b0, agg->xc, gemm in place over xc
    k_agg<<<(NN * 64) / 256, 256, 0, stream>>>((const u32*)b0, offs, ssrc, invdeg, (u32*)xc);
    k_gemm<<<gblk, 256, 0, stream>>>(b0, xc,
            Wl + HH * HH, Wr + HH * HH, bl + HH, gam + HH, bet + HH, 1);
    // layer 2: X=xc, agg->b0, gemm in place over b0
    k_agg<<<(NN * 64) / 256, 256, 0, stream>>>((const u32*)xc, offs, ssrc, invdeg, (u32*)b0);
    k_gemm<<<gblk, 256, 0, stream>>>(xc, b0,
            Wl + 2 * HH * HH, Wr + 2 * HH * HH, bl + 2 * HH, gam + 2 * HH, bet + 2 * HH, 1);

    k_proj<<<gblk, 256, 0, stream>>>(b0, Wo, bo, d_out, flags);
}

// Round 5
// 441.589 us; speedup vs baseline: 2.4244x; 1.4423x over previous
//
#include <hip/hip_runtime.h>
#include <hip/hip_bf16.h>

#define NN 100000
#define NE 625000
#define HH 128
#define DOUT 64
#define NHTOT (NN * HH)          // 12,800,000 feature elements
#define SCAN_B 391               // ceil(NN/256)
#define WTOT 107712              // canonical weight element count

// canonical weight offsets (elements)
#define OW_Wl  0
#define OW_bl  49152
#define OW_Wr  49536
#define OW_gam 98688
#define OW_bet 99072
#define OW_Wo  99456
#define OW_bo  107648

typedef unsigned int u32;
typedef unsigned short u16;
typedef long long i64;
typedef short bf16x8 __attribute__((ext_vector_type(8)));   // 8 bf16 = 4 VGPR
typedef float f32x4 __attribute__((ext_vector_type(4)));

__device__ __forceinline__ float bflo(u32 v) { return __uint_as_float(v << 16); }
__device__ __forceinline__ float bfhi(u32 v) { return __uint_as_float(v & 0xffff0000u); }
__device__ __forceinline__ float bf2f(u16 u) { return __uint_as_float(((u32)u) << 16); }
__device__ __forceinline__ u16 f2b(float f) {
    __hip_bfloat16 h = __float2bfloat16(f);   // RNE
    return *(u16*)&h;
}
__device__ __forceinline__ int edge_at(const void* ei, int is64, i64 idx) {
    return is64 ? (int)((const i64*)ei)[idx] : ((const int*)ei)[idx];
}

// ---- dtype sniffer: flags[0]=1 if x is fp32, flags[1]=1 if edge_index is int64 ----
__global__ void k_sniff(const u16* __restrict__ x, const int* __restrict__ ei,
                        int* __restrict__ flags) {
    __shared__ int cbad, cnz;
    int t = threadIdx.x;
    if (t == 0) { cbad = 0; cnz = 0; }
    __syncthreads();
    u16 u = x[t];
    int e = (u >> 7) & 0xff;            // bf16 exponent field
    if (e >= 132) atomicAdd(&cbad, 1);
    if (t < 32) { if (ei[2 * t + 1] != 0) atomicAdd(&cnz, 1); }
    __syncthreads();
    if (t == 0) {
        flags[0] = (cbad > 4) ? 1 : 0;  // fp32 floats
        flags[1] = (cnz == 0) ? 1 : 0;  // int64 edges
    }
}

// ---- canonicalize x -> bf16 buffer ----
__global__ void k_cvt(const void* __restrict__ xin, uint2* __restrict__ out,
                      const int* __restrict__ flags) {
    int gid = blockIdx.x * 256 + threadIdx.x;   // grid = NHTOT/4/256 exact
    if (flags[0]) {
        float4 v = ((const float4*)xin)[gid];
        uint2 r;
        r.x = (u32)f2b(v.x) | ((u32)f2b(v.y) << 16);
        r.y = (u32)f2b(v.z) | ((u32)f2b(v.w) << 16);
        out[gid] = r;
    } else {
        out[gid] = ((const uint2*)xin)[gid];
    }
}

// ---- canonicalize all weights/biases -> bf16 ----
__global__ void k_cvtw(const void* Wl, const void* bl, const void* Wr,
                       const void* gam, const void* bet, const void* Wo,
                       const void* bo, u16* __restrict__ wc,
                       const int* __restrict__ flags) {
    int gid = blockIdx.x * 256 + threadIdx.x;
    if (gid >= WTOT) return;
    const void* p; int li;
    if      (gid < OW_bl)  { p = Wl;  li = gid; }
    else if (gid < OW_Wr)  { p = bl;  li = gid - OW_bl; }
    else if (gid < OW_gam) { p = Wr;  li = gid - OW_Wr; }
    else if (gid < OW_bet) { p = gam; li = gid - OW_gam; }
    else if (gid < OW_Wo)  { p = bet; li = gid - OW_bet; }
    else if (gid < OW_bo)  { p = Wo;  li = gid - OW_Wo; }
    else                   { p = bo;  li = gid - OW_bo; }
    wc[gid] = flags[0] ? f2b(((const float*)p)[li]) : ((const u16*)p)[li];
}

// ---- degree histogram over dst ----
__global__ void k_hist(const void* __restrict__ ei, int* __restrict__ cnt,
                       const int* __restrict__ flags) {
    int e = blockIdx.x * 256 + threadIdx.x;
    if (e < NE) {
        int d = edge_at(ei, flags[1], (i64)NE + e);
        if ((unsigned)d < NN) atomicAdd(&cnt[d], 1);
    }
}

// ---- scan step 1: per-block sums ----
__global__ void k_scan1(const int* __restrict__ cnt, int* __restrict__ part) {
    __shared__ int sh[256];
    int t = threadIdx.x, g = blockIdx.x * 256 + t;
    sh[t] = (g < NN) ? cnt[g] : 0;
    __syncthreads();
    for (int s = 128; s > 0; s >>= 1) { if (t < s) sh[t] += sh[t + s]; __syncthreads(); }
    if (t == 0) part[blockIdx.x] = sh[0];
}

// ---- scan step 2: exclusive scan of SCAN_B partials ----
__global__ void k_scan2(int* part) {
    __shared__ int sh[512];
    int t = threadIdx.x;
    int v = (t < SCAN_B) ? part[t] : 0;
    sh[t] = v; __syncthreads();
    for (int off = 1; off < 512; off <<= 1) {
        int a = (t >= off) ? sh[t - off] : 0;
        __syncthreads(); sh[t] += a; __syncthreads();
    }
    if (t < SCAN_B) part[t] = sh[t] - v;   // exclusive
}

// ---- scan step 3: offsets, cursor, invdeg ----
__global__ void k_scan3(const int* __restrict__ cnt, const int* __restrict__ part,
                        int* __restrict__ offs, int* __restrict__ cur,
                        float* __restrict__ invdeg) {
    __shared__ int sh[256];
    int t = threadIdx.x, g = blockIdx.x * 256 + t;
    int c = (g < NN) ? cnt[g] : 0;
    sh[t] = c; __syncthreads();
    for (int off = 1; off < 256; off <<= 1) {
        int a = (t >= off) ? sh[t - off] : 0;
        __syncthreads(); sh[t] += a; __syncthreads();
    }
    if (g < NN) {
        int start = part[blockIdx.x] + sh[t] - c;
        offs[g] = start; cur[g] = start;
        invdeg[g] = 1.0f / fmaxf((float)c, 1.0f);
        if (g == NN - 1) offs[NN] = start + c;
    }
}

// ---- counting-sort src by dst ----
__global__ void k_sort(const void* __restrict__ ei, int* __restrict__ cur,
                       int* __restrict__ ssrc, const int* __restrict__ flags) {
    int e = blockIdx.x * 256 + threadIdx.x;
    if (e < NE) {
        int is64 = flags[1];
        int d = edge_at(ei, is64, (i64)NE + e);
        int s = edge_at(ei, is64, (i64)e);
        if ((unsigned)d < NN) {
            int p = atomicAdd(&cur[d], 1);
            if ((unsigned)p < NE) ssrc[p] = s;
        }
    }
}

// ---- aggregation: one wave per dst node; index prefetch + 4x unrolled gather ----
__global__ void k_agg(const u32* __restrict__ X, const int* __restrict__ offs,
                      const int* __restrict__ ssrc, const float* __restrict__ invdeg,
                      u32* __restrict__ AGG) {
    int wid = (blockIdx.x * 256 + threadIdx.x) >> 6;
    int lane = threadIdx.x & 63;
    if (wid >= NN) return;
    int s0 = offs[wid], s1 = offs[wid + 1];
    float a0 = 0.f, a1 = 0.f;
    for (int base = s0; base < s1; base += 64) {
        int cnt = min(64, s1 - base);
        int idx = ssrc[base + min(lane, cnt - 1)];   // coalesced index prefetch
        idx = min(max(idx, 0), NN - 1);
        int j = 0;
        for (; j + 4 <= cnt; j += 4) {
            int i0 = __shfl(idx, j), i1 = __shfl(idx, j + 1);
            int i2 = __shfl(idx, j + 2), i3 = __shfl(idx, j + 3);
            u32 v0 = X[(size_t)i0 * 64 + lane];
            u32 v1 = X[(size_t)i1 * 64 + lane];
            u32 v2 = X[(size_t)i2 * 64 + lane];
            u32 v3 = X[(size_t)i3 * 64 + lane];
            a0 += bflo(v0) + bflo(v1) + bflo(v2) + bflo(v3);
            a1 += bfhi(v0) + bfhi(v1) + bfhi(v2) + bfhi(v3);
        }
        for (; j < cnt; ++j) {
            u32 v = X[(size_t)__shfl(idx, j) * 64 + lane];
            a0 += bflo(v); a1 += bfhi(v);
        }
    }
    float iv = invdeg[wid];
    u32 r = (u32)f2b(a0 * iv) | ((u32)f2b(a1 * iv) << 16);
    AGG[(size_t)wid * 64 + lane] = r;
}

// ---- MFMA fused dual-GEMM + bias + residual + LayerNorm + ReLU ----
// Block = 256 thr = 4 waves, 128 nodes. Wl+Wr staged in 64 KB LDS, laid out so
// each (ft,kt) B-fragment read is 64 lanes x 16B contiguous (conflict-free
// ds_read_b128). Each wave: 32 nodes as two 16-node groups sharing B-frags.
// A: lane m=mn -> node, k=kt*32+quad*8+j. C/D: row(node)=quad*4+r, col=mn.
__global__ __launch_bounds__(256, 2) void k_gemm(
        const u16* __restrict__ X, u16* __restrict__ AGG,
        const u16* __restrict__ Wl, const u16* __restrict__ Wr,
        const u16* __restrict__ bl, const u16* __restrict__ gam,
        const u16* __restrict__ bet, int residual) {
    // WS[m][ft][kt][quad][mn][8] : 2*8*4*4*16*8 u16 = 64 KB
    __shared__ __align__(16) u16 WS[32768];
    int tid = threadIdx.x;
    int wave = tid >> 6, lane = tid & 63;
    int mn = lane & 15, quad = lane >> 4;
    int n0w = blockIdx.x * 128 + wave * 32;

    // stage both W matrices into LDS
    #pragma unroll
    for (int it = 0; it < 16; ++it) {
        int cid = it * 256 + tid;               // 0..4095 16B-chunks
        int m = cid >> 11, r = cid & 2047;
        int ft = r >> 8, kt = (r >> 6) & 3, q = (r >> 4) & 3, f16 = r & 15;
        const u16* src = (m ? Wr : Wl) + (size_t)(ft * 16 + f16) * HH + kt * 32 + q * 8;
        *(bf16x8*)&WS[cid * 8] = *(const bf16x8*)src;
    }

    // A fragments for 2 node groups (AGG and X), while staging is in flight
    bf16x8 afrA[2][4], afrX[2][4];
    #pragma unroll
    for (int g = 0; g < 2; ++g) {
        int ngc = min(n0w + g * 16 + mn, NN - 1);
        const u16* ar = AGG + (size_t)ngc * HH;
        const u16* xr = X   + (size_t)ngc * HH;
        #pragma unroll
        for (int kt = 0; kt < 4; ++kt) {
            afrA[g][kt] = *(const bf16x8*)(ar + kt * 32 + quad * 8);
            afrX[g][kt] = *(const bf16x8*)(xr + kt * 32 + quad * 8);
        }
    }

    f32x4 acc[8][2];
    #pragma unroll
    for (int ft = 0; ft < 8; ++ft)
        #pragma unroll
        for (int g = 0; g < 2; ++g) acc[ft][g] = (f32x4){0.f, 0.f, 0.f, 0.f};

    __syncthreads();

    int laneoff = (quad * 16 + mn) * 8;
    #pragma unroll
    for (int ft = 0; ft < 8; ++ft) {
        #pragma unroll
        for (int kt = 0; kt < 4; ++kt) {
            bf16x8 b = *(const bf16x8*)&WS[(ft * 4 + kt) * 512 + laneoff];
            acc[ft][0] = __builtin_amdgcn_mfma_f32_16x16x32_bf16(afrA[0][kt], b, acc[ft][0], 0, 0, 0);
            acc[ft][1] = __builtin_amdgcn_mfma_f32_16x16x32_bf16(afrA[1][kt], b, acc[ft][1], 0, 0, 0);
        }
        #pragma unroll
        for (int kt = 0; kt < 4; ++kt) {
            bf16x8 b = *(const bf16x8*)&WS[(32 + ft * 4 + kt) * 512 + laneoff];
            acc[ft][0] = __builtin_amdgcn_mfma_f32_16x16x32_bf16(afrX[0][kt], b, acc[ft][0], 0, 0, 0);
            acc[ft][1] = __builtin_amdgcn_mfma_f32_16x16x32_bf16(afrX[1][kt], b, acc[ft][1], 0, 0, 0);
        }
    }

    // epilogue per node group: bias + residual + LN + relu
    #pragma unroll
    for (int g = 0; g < 2; ++g) {
        int nb = n0w + g * 16;
        float s1[4] = {0, 0, 0, 0}, s2[4] = {0, 0, 0, 0};
        #pragma unroll
        for (int ft = 0; ft < 8; ++ft) {
            int f = ft * 16 + mn;
            float bv = bf2f(bl[f]);
            #pragma unroll
            for (int r = 0; r < 4; ++r) {
                int ndc = min(nb + quad * 4 + r, NN - 1);
                float res = residual ? bf2f(X[(size_t)ndc * HH + f]) : 0.f;
                float v = acc[ft][g][r] + bv + res;
                acc[ft][g][r] = v;
                s1[r] += v; s2[r] += v * v;
            }
        }
        #pragma unroll
        for (int msk = 1; msk < 16; msk <<= 1) {
            #pragma unroll
            for (int r = 0; r < 4; ++r) {
                s1[r] += __shfl_xor(s1[r], msk, 64);
                s2[r] += __shfl_xor(s2[r], msk, 64);
            }
        }
        #pragma unroll
        for (int r = 0; r < 4; ++r) {
            float mu = s1[r] * (1.0f / 128.0f);
            float var = s2[r] * (1.0f / 128.0f) - mu * mu;
            float rs = rsqrtf(fmaxf(var, 0.f) + 1e-5f);
            s1[r] = mu; s2[r] = rs;
        }
        #pragma unroll
        for (int ft = 0; ft < 8; ++ft) {
            int f = ft * 16 + mn;
            float gm = bf2f(gam[f]), bt = bf2f(bet[f]);
            #pragma unroll
            for (int r = 0; r < 4; ++r) {
                int nd = nb + quad * 4 + r;
                if (nd < NN) {
                    float v = (acc[ft][g][r] - s1[r]) * s2[r] * gm + bt;
                    AGG[(size_t)nd * HH + f] = f2b(fmaxf(v, 0.f));
                }
            }
        }
    }
}

// ---- MFMA final projection: out = x3 @ Wo^T + bo ----
__global__ __launch_bounds__(256) void k_proj(
        const u16* __restrict__ Xf, const u16* __restrict__ Wo,
        const u16* __restrict__ bo, void* __restrict__ out,
        const int* __restrict__ flags) {
    int tid = threadIdx.x;
    int wave = tid >> 6, lane = tid & 63;
    int mn = lane & 15, quad = lane >> 4;
    int n0 = (blockIdx.x * 4 + wave) * 16;
    if (n0 >= NN) return;

    int ngc = min(n0 + mn, NN - 1);
    const u16* xrow = Xf + (size_t)ngc * HH;
    bf16x8 afr[4];
    #pragma unroll
    for (int kt = 0; kt < 4; ++kt)
        afr[kt] = *(const bf16x8*)(xrow + kt * 32 + quad * 8);

    f32x4 acc[4];
    #pragma unroll
    for (int ft = 0; ft < 4; ++ft) acc[ft] = (f32x4){0.f, 0.f, 0.f, 0.f};
    #pragma unroll
    for (int ft = 0; ft < 4; ++ft) {
        const u16* worow = Wo + (size_t)(ft * 16 + mn) * HH;
        #pragma unroll
        for (int kt = 0; kt < 4; ++kt) {
            bf16x8 b = *(const bf16x8*)(worow + kt * 32 + quad * 8);
            acc[ft] = __builtin_amdgcn_mfma_f32_16x16x32_bf16(afr[kt], b, acc[ft], 0, 0, 0);
        }
    }
    int isf32 = flags[0];
    #pragma unroll
    for (int ft = 0; ft < 4; ++ft) {
        int f = ft * 16 + mn;
        float bv = bf2f(bo[f]);
        #pragma unroll
        for (int r = 0; r < 4; ++r) {
            int nd = n0 + quad * 4 + r;
            if (nd < NN) {
                float v = acc[ft][r] + bv;
                if (isf32) ((float*)out)[(size_t)nd * DOUT + f] = v;
                else       ((u16*)out)[(size_t)nd * DOUT + f]   = f2b(v);
            }
        }
    }
}

extern "C" void kernel_launch(void* const* d_in, const int* in_sizes, int n_in,
                              void* d_out, int out_size, void* d_ws, size_t ws_size,
                              hipStream_t stream) {
    const void* xin = d_in[0];
    const void* ei  = d_in[1];     // [2][NE]: row0=src, row1=dst

    u16*   xc     = (u16*)d_ws;                 // NHTOT bf16
    u16*   b0     = xc + NHTOT;                 // NHTOT bf16
    u16*   wc     = b0 + NHTOT;                 // WTOT (padded to 107776)
    float* invdeg = (float*)(wc + 107776);      // NN
    int*   cnt    = (int*)(invdeg + NN);        // NN
    int*   cur    = cnt + NN;                   // NN
    int*   offs   = cur + NN;                   // NN+1
    int*   ssrc   = offs + NN + 1;              // NE
    int*   part   = ssrc + NE;                  // 512
    int*   flags  = part + 512;                 // 2

    k_sniff<<<1, 256, 0, stream>>>((const u16*)xin, (const int*)ei, flags);
    hipMemsetAsync(cnt, 0, NN * sizeof(int), stream);
    hipMemsetAsync(ssrc, 0, NE * sizeof(int), stream);
    k_cvt <<<NHTOT / 4 / 256, 256, 0, stream>>>(xin, (uint2*)xc, flags);
    k_cvtw<<<(WTOT + 255) / 256, 256, 0, stream>>>(d_in[2], d_in[3], d_in[4],
            d_in[5], d_in[6], d_in[7], d_in[8], wc, flags);
    k_hist<<<(NE + 255) / 256, 256, 0, stream>>>(ei, cnt, flags);
    k_scan1<<<SCAN_B, 256, 0, stream>>>(cnt, part);
    k_scan2<<<1, 512, 0, stream>>>(part);
    k_scan3<<<SCAN_B, 256, 0, stream>>>(cnt, part, offs, cur, invdeg);
    k_sort<<<(NE + 255) / 256, 256, 0, stream>>>(ei, cur, ssrc, flags);

    const u16* Wl  = wc + OW_Wl;
    const u16* bl  = wc + OW_bl;
    const u16* Wr  = wc + OW_Wr;
    const u16* gam = wc + OW_gam;
    const u16* bet = wc + OW_bet;
    const u16* Wo  = wc + OW_Wo;
    const u16* bo  = wc + OW_bo;

    int gblk = (NN + 127) / 128;   // 128 nodes per block (4 waves x 32)
    // layer 0: X=xc, agg->b0, gemm in place over b0
    k_agg<<<(NN * 64) / 256, 256, 0, stream>>>((const u32*)xc, offs, ssrc, invdeg, (u32*)b0);
    k_gemm<<<gblk, 256, 0, stream>>>(xc, b0, Wl, Wr, bl, gam, bet, 0);
    // layer 1: X=b0, agg->xc, gemm in place over xc
    k_agg<<<(NN * 64) / 256, 256, 0, stream>>>((const u32*)b0, offs, ssrc, invdeg, (u32*)xc);
    k_gemm<<<gblk, 256, 0, stream>>>(b0, xc,
            Wl + HH * HH, Wr + HH * HH, bl + HH, gam + HH, bet + HH, 1);
    // layer 2: X=xc, agg->b0, gemm in place over b0
    k_agg<<<(NN * 64) / 256, 256, 0, stream>>>((const u32*)xc, offs, ssrc, invdeg, (u32*)b0);
    k_gemm<<<gblk, 256, 0, stream>>>(xc, b0,
            Wl + 2 * HH * HH, Wr + 2 * HH * HH, bl + 2 * HH, gam + 2 * HH, bet + 2 * HH, 1);

    k_proj<<<(NN + 63) / 64, 256, 0, stream>>>(b0, Wo, bo, d_out, flags);
}